// Round 3
// baseline (80.527 us; speedup 1.0000x reference)
//
#include <hip/hip_runtime.h>
#include <math.h>

#define RADIUS 0.05f
#define NSLICE 8          // point-slices per render block (waves)
#define TCAP  160         // per-tile candidate capacity (E=67, +11 sigma)
#define HCAP  40          // per-pixel hit capacity (E=8, Poisson tail ~1e-18)
#define HSTR  41          // padded stride: 41 mod 32 = 9, gcd(9,32)=1 -> spread banks

// ---------------- kernel 0: zero per-tile counters ----------------
__global__ __launch_bounds__(256) void zero_counts(int* __restrict__ cnts, int n) {
    int i = blockIdx.x * 256 + threadIdx.x;
    if (i < n) cnts[i] = 0;
}

// ---------------- kernel 1: bin points into per-tile lists ----------------
// One thread per point: project once, push to every tile whose pixel centers
// could be within RADIUS (conservative 1-px widened range).
__global__ __launch_bounds__(256) void bin_points(
    const float* __restrict__ points, int N, int H, int W,
    int tiles_x, int tiles_y,
    int* __restrict__ cnts, float4* __restrict__ lists)
{
    int i = blockIdx.x * 256 + threadIdx.x;
    if (i >= N) return;
    float x = points[3 * i + 0];
    float y = points[3 * i + 1];
    float z = points[3 * i + 2];
    if (z <= 0.0f) return;
    float px = x / z;
    float py = y / z;

    // pixel ix has center cx = (ix+0.5)*(2/W)-1; hit possible iff |cx-px|<=R.
    // floor(lo) / floor(hi)+1 widens by ~1px each side -> conservative vs fp.
    const float invsx = (float)W * 0.5f;
    const float invsy = (float)H * 0.5f;
    int ix0 = (int)floorf((px - RADIUS + 1.0f) * invsx - 0.5f);
    int ix1 = (int)floorf((px + RADIUS + 1.0f) * invsx - 0.5f) + 1;
    int iy0 = (int)floorf((py - RADIUS + 1.0f) * invsy - 0.5f);
    int iy1 = (int)floorf((py + RADIUS + 1.0f) * invsy - 0.5f) + 1;
    ix0 = max(ix0, 0); iy0 = max(iy0, 0);
    ix1 = min(ix1, W - 1); iy1 = min(iy1, H - 1);
    if (ix0 > ix1 || iy0 > iy1) return;

    int tx0 = ix0 >> 3, tx1 = ix1 >> 3;
    int ty0 = iy0 >> 3, ty1 = iy1 >> 3;
    float4 rec = make_float4(px, py, z, __int_as_float(i));
    for (int ty = ty0; ty <= ty1; ty++) {
        for (int tx = tx0; tx <= tx1; tx++) {
            int t = ty * tiles_x + tx;
            int pos = atomicAdd(&cnts[t], 1);   // device-scope
            if (pos < TCAP) lists[(size_t)t * TCAP + pos] = rec;
        }
    }
}

// ---------------- kernel 2: render one 8x8 tile per block ----------------
__global__ __launch_bounds__(512) void render_tiles(
    const float* __restrict__ features,  // [N,8]
    float* __restrict__ out,             // [H,W,8]
    int H, int W, int tiles_x,
    const int* __restrict__ cnts, const float4* __restrict__ lists)
{
    const float r2 = RADIUS * RADIUS;
    const float inv_r2 = 1.0f / r2;

    __shared__ float4 sp[TCAP];
    __shared__ float  s_hz[64 * HSTR];
    __shared__ float  s_hd[64 * HSTR];
    __shared__ int    s_hi[64 * HSTR];
    __shared__ int    s_pcnt[64];

    const int tile = blockIdx.x;
    const int cnt = min(cnts[tile], TCAP);

    if (threadIdx.x < 64) s_pcnt[threadIdx.x] = 0;
    // stage this tile's candidate list into LDS (coalesced, ~1 iteration)
    for (int i = threadIdx.x; i < cnt; i += 512)
        sp[i] = lists[(size_t)tile * TCAP + i];
    __syncthreads();

    const int tx = tile % tiles_x;
    const int ty = tile / tiles_x;
    const int x0i = tx * 8;
    const int y0i = ty * 8;
    const float sx = 2.0f / (float)W;
    const float sy = 2.0f / (float)H;

    const int pxl = threadIdx.x & 63;     // pixel within tile == lane
    const int slice = threadIdx.x >> 6;   // 0..7 == wave id
    const int ix = x0i + (pxl & 7);
    const int iy = y0i + (pxl >> 3);
    const float gx = ((float)ix + 0.5f) * sx - 1.0f;
    const float gy = ((float)iy + 0.5f) * sy - 1.0f;

    // ---- sliced scan, append hits per pixel ----
    for (int c = slice; c < cnt; c += NSLICE) {
        float4 q = sp[c];   // same addr across wave -> broadcast, conflict-free
        float dx = gx - q.x;
        float dy = gy - q.y;
        float d2 = dx * dx + dy * dy;
        if (d2 < r2) {
            int pos = atomicAdd(&s_pcnt[pxl], 1);
            if (pos < HCAP) {
                s_hz[pxl * HSTR + pos] = q.z;
                s_hd[pxl * HSTR + pos] = d2;
                s_hi[pxl * HSTR + pos] = __float_as_int(q.w);
            }
        }
    }
    __syncthreads();

    // ---- per-pixel top-8 by depth + composite (wave 0 only) ----
    if (threadIdx.x < 64) {
        const int m = min(s_pcnt[pxl], HCAP);
        float zk[8];
        int sk[8];
#pragma unroll
        for (int k = 0; k < 8; k++) { zk[k] = 3.0e38f; sk[k] = 0; }

        for (int i = 0; i < m; i++) {
            float z = s_hz[pxl * HSTR + i];
            if (z < zk[7]) {
                int s = i;
#pragma unroll
                for (int k = 0; k < 8; k++) {
                    bool lt = z < zk[k];   // strict <, z distinct -> order-independent
                    float tz = zk[k];
                    int ts = sk[k];
                    if (lt) { zk[k] = z; sk[k] = s; z = tz; s = ts; }
                }
            }
        }

        float acc0 = 0.f, acc1 = 0.f, acc2 = 0.f, acc3 = 0.f;
        float acc4 = 0.f, acc5 = 0.f, acc6 = 0.f, acc7 = 0.f;
        float T = 1.0f;
#pragma unroll
        for (int k = 0; k < 8; k++) {
            if (zk[k] < 1.0e30f) {
                float d2 = s_hd[pxl * HSTR + sk[k]];
                int   id = s_hi[pxl * HSTR + sk[k]];
                float alpha = 1.0f - d2 * inv_r2;
                alpha = fminf(fmaxf(alpha, 0.0f), 1.0f);
                float w = alpha * T;
                T *= (1.0f - alpha);
                const float4* f = (const float4*)(features + (size_t)id * 8);
                float4 f0 = f[0];
                float4 f1 = f[1];
                acc0 += w * f0.x; acc1 += w * f0.y; acc2 += w * f0.z; acc3 += w * f0.w;
                acc4 += w * f1.x; acc5 += w * f1.y; acc6 += w * f1.z; acc7 += w * f1.w;
            }
        }

        if (ix < W && iy < H) {
            float4* o = (float4*)(out + (size_t)(iy * W + ix) * 8);
            o[0] = make_float4(acc0, acc1, acc2, acc3);
            o[1] = make_float4(acc4, acc5, acc6, acc7);
        }
    }
}

extern "C" void kernel_launch(void* const* d_in, const int* in_sizes, int n_in,
                              void* d_out, int out_size, void* d_ws, size_t ws_size,
                              hipStream_t stream) {
    const float* points = (const float*)d_in[0];
    const float* features = (const float*)d_in[1];
    float* out = (float*)d_out;

    int N = in_sizes[0] / 3;                // 4096
    int C = in_sizes[1] / N;                // 8 (kernel assumes 8)
    int P = out_size / C;                   // 16384
    int H = (int)(sqrt((double)P) + 0.5);   // 128
    int W = H;
    int tiles_x = (W + 7) / 8;
    int tiles_y = (H + 7) / 8;
    int n_tiles = tiles_x * tiles_y;        // 256

    // workspace layout: [0,1KB) tile counters, [1KB, ...) tile lists
    int* cnts = (int*)d_ws;
    float4* lists = (float4*)((char*)d_ws + 1024);

    zero_counts<<<(n_tiles + 255) / 256, 256, 0, stream>>>(cnts, n_tiles);
    bin_points<<<(N + 255) / 256, 256, 0, stream>>>(points, N, H, W,
                                                    tiles_x, tiles_y, cnts, lists);
    render_tiles<<<n_tiles, 512, 0, stream>>>(features, out, H, W, tiles_x, cnts, lists);
}

// Round 4
// 71.699 us; speedup vs baseline: 1.1231x; 1.1231x over previous
//
#include <hip/hip_runtime.h>
#include <math.h>

#define RADIUS 0.05f
#define NTHREADS 1024     // 16 waves/block -> 4 waves/SIMD at 1 block/CU
#define NSLICE   16       // point-slices per tile = waves per block
#define SPCAP   256       // per-tile candidate capacity (E=67; overflow P ~ e^-46)
#define HCAP    40        // per-pixel hit capacity (E=8, Poisson tail ~1e-18)
#define HSTR    41        // stride 41 dwords: 41 mod 32 = 9, gcd(9,32)=1 -> conflict-free

// One block = one 8x8 pixel tile, 1024 threads = 64 pixels x 16 point-slices.
// Phase 1: div-free cull of all N points (x >= bx0*z etc.), rcp only for survivors.
// Phase 2: sliced scan (16 slices), hits appended to per-pixel LDS lists.
// Phase 3: wave 0, 1 thread/pixel: top-8-by-z insertion, composite, store.
__global__ __launch_bounds__(1024) void render_tiles(
    const float* __restrict__ points,    // [N,3] camera space
    const float* __restrict__ features,  // [N,8]
    float* __restrict__ out,             // [H,W,8]
    int N, int H, int W, int tiles_x)
{
    const float r2 = RADIUS * RADIUS;
    const float inv_r2 = 1.0f / r2;

    __shared__ float4 sp[SPCAP];          // (px, py, z, idx-as-float)
    __shared__ float  s_hz[64 * HSTR];
    __shared__ float  s_hd[64 * HSTR];
    __shared__ int    s_hi[64 * HSTR];
    __shared__ int    s_pcnt[64];
    __shared__ int    s_cnt;

    if (threadIdx.x == 0) s_cnt = 0;
    if (threadIdx.x < 64) s_pcnt[threadIdx.x] = 0;
    __syncthreads();

    const int tile = blockIdx.x;
    const int tx = tile % tiles_x;
    const int ty = tile / tiles_x;
    const int x0i = tx * 8, y0i = ty * 8;
    const float sx = 2.0f / (float)W, sy = 2.0f / (float)H;
    // tile pixel-center NDC bounds, expanded by splat radius (conservative)
    const float bx0 = ((float)x0i + 0.5f) * sx - 1.0f - RADIUS;
    const float bx1 = ((float)(x0i + 7) + 0.5f) * sx - 1.0f + RADIUS;
    const float by0 = ((float)y0i + 0.5f) * sy - 1.0f - RADIUS;
    const float by1 = ((float)(y0i + 7) + 0.5f) * sy - 1.0f + RADIUS;

    // ---- Phase 1: div-free cull (px>=bx0 <=> x>=bx0*z since z>0) ----
    for (int i = threadIdx.x; i < N; i += NTHREADS) {
        float x = points[3 * i + 0];
        float y = points[3 * i + 1];
        float z = points[3 * i + 2];
        bool keep = (z > 0.0f) & (x >= bx0 * z) & (x <= bx1 * z)
                               & (y >= by0 * z) & (y <= by1 * z);
        if (keep) {
            float rz = __builtin_amdgcn_rcpf(z);   // ~1ulp; error << alpha threshold
            int pos = atomicAdd(&s_cnt, 1);
            if (pos < SPCAP) sp[pos] = make_float4(x * rz, y * rz, z, __int_as_float(i));
        }
    }
    __syncthreads();
    const int cnt = min(s_cnt, SPCAP);

    // ---- Phase 2: sliced scan, append hits per pixel (pipelined LDS reads) ----
    const int pxl = threadIdx.x & 63;
    const int slice = threadIdx.x >> 6;   // 0..15
    const int ix = x0i + (pxl & 7);
    const int iy = y0i + (pxl >> 3);
    const float gx = ((float)ix + 0.5f) * sx - 1.0f;
    const float gy = ((float)iy + 0.5f) * sy - 1.0f;

    int c = slice;
    if (c < cnt) {
        float4 q = sp[c];                 // broadcast across wave, conflict-free
        while (true) {
            int cn = c + NSLICE;
            bool more = cn < cnt;
            float4 qn = sp[more ? cn : slice];   // prefetch next before processing
            float dx = gx - q.x;
            float dy = gy - q.y;
            float d2 = dx * dx + dy * dy;
            if (d2 < r2) {
                int pos = atomicAdd(&s_pcnt[pxl], 1);
                if (pos < HCAP) {
                    s_hz[pxl * HSTR + pos] = q.z;
                    s_hd[pxl * HSTR + pos] = d2;
                    s_hi[pxl * HSTR + pos] = __float_as_int(q.w);
                }
            }
            if (!more) break;
            q = qn; c = cn;
        }
    }
    __syncthreads();

    // ---- Phase 3: per-pixel top-8 by depth + composite (wave 0 only) ----
    if (threadIdx.x < 64) {
        const int m = min(s_pcnt[pxl], HCAP);
        float zk[8];
        int sk[8];
#pragma unroll
        for (int k = 0; k < 8; k++) { zk[k] = 3.0e38f; sk[k] = 0; }

        float z_next = s_hz[pxl * HSTR];            // safe: garbage if m==0, unused
        for (int i = 0; i < m; i++) {
            float z = z_next;
            z_next = s_hz[pxl * HSTR + i + 1];      // prefetch (i+1 < HSTR, in-bounds)
            if (z < zk[7]) {
                int s = i;
#pragma unroll
                for (int k = 0; k < 8; k++) {
                    bool lt = z < zk[k];   // strict <, z distinct -> order-independent
                    float tz = zk[k];
                    int ts = sk[k];
                    if (lt) { zk[k] = z; sk[k] = s; z = tz; s = ts; }
                }
            }
        }

        float acc0 = 0.f, acc1 = 0.f, acc2 = 0.f, acc3 = 0.f;
        float acc4 = 0.f, acc5 = 0.f, acc6 = 0.f, acc7 = 0.f;
        float T = 1.0f;
#pragma unroll
        for (int k = 0; k < 8; k++) {
            if (zk[k] < 1.0e30f) {
                float d2 = s_hd[pxl * HSTR + sk[k]];
                int   id = s_hi[pxl * HSTR + sk[k]];
                float alpha = 1.0f - d2 * inv_r2;
                alpha = fminf(fmaxf(alpha, 0.0f), 1.0f);
                float w = alpha * T;
                T *= (1.0f - alpha);
                const float4* f = (const float4*)(features + (size_t)id * 8);
                float4 f0 = f[0];
                float4 f1 = f[1];
                acc0 += w * f0.x; acc1 += w * f0.y; acc2 += w * f0.z; acc3 += w * f0.w;
                acc4 += w * f1.x; acc5 += w * f1.y; acc6 += w * f1.z; acc7 += w * f1.w;
            }
        }

        if (ix < W && iy < H) {
            float4* o = (float4*)(out + (size_t)(iy * W + ix) * 8);
            o[0] = make_float4(acc0, acc1, acc2, acc3);
            o[1] = make_float4(acc4, acc5, acc6, acc7);
        }
    }
}

extern "C" void kernel_launch(void* const* d_in, const int* in_sizes, int n_in,
                              void* d_out, int out_size, void* d_ws, size_t ws_size,
                              hipStream_t stream) {
    const float* points = (const float*)d_in[0];
    const float* features = (const float*)d_in[1];
    float* out = (float*)d_out;

    int N = in_sizes[0] / 3;                // 4096
    int C = in_sizes[1] / N;                // 8 (kernel assumes 8)
    int P = out_size / C;                   // 16384
    int H = (int)(sqrt((double)P) + 0.5);   // 128
    int W = H;
    int tiles_x = (W + 7) / 8;
    int tiles_y = (H + 7) / 8;

    render_tiles<<<tiles_x * tiles_y, NTHREADS, 0, stream>>>(points, features, out,
                                                             N, H, W, tiles_x);
}